// Round 6
// baseline (790.757 us; speedup 1.0000x reference)
//
#include <hip/hip_runtime.h>
#include <hip/hip_bf16.h>

typedef __attribute__((ext_vector_type(8))) short short8;
typedef __attribute__((ext_vector_type(4))) float floatx4;

#define TINV 14.2857142857142857f               // 1/0.07
#define TL2  20.60992915555662f                  // TINV * log2(e)
#define LN2  0.6931471805599453f
#define SQS  4.539816022451927f                  // sqrt(TL2): dot(fb,fb) = TL2*dot(f,f)
#define NROWS 8192
#define NDIM 128
#define NCH 32                                   // 32 chunks x 256 cols
#define NITS 8                                   // 8 x 32 cols per chunk
#define CLASS_COEF (1.0f / (8192.0f * 3.0f))
#define NOISE_COEF (-LN2 / (57344.0f * 0.07f * 3.0f))

__device__ __forceinline__ float fexp2(float x) {
#if __has_builtin(__builtin_amdgcn_exp2f)
    return __builtin_amdgcn_exp2f(x);
#else
    return __expf(x * LN2);
#endif
}

// fp32 -> bf16 (pre-scaled by sqrt(TL2)) transposed into fbT[(kc*8192+row)*8];
// block 0 additionally computes pcount[512] and zeroes out + rbcnt.
__global__ void prep_kernel(const float* __restrict__ in, const int* __restrict__ labels,
                            unsigned short* __restrict__ fbT, float* __restrict__ pcount,
                            int* __restrict__ rbcnt, float* __restrict__ out) {
    const int tid = threadIdx.x;
    const int i = blockIdx.x * 256 + tid;       // 512 blocks: 131072 = 16 kc x 8192 rows
    const int kc = i >> 13;
    const int row = i & 8191;
    const float4* p = (const float4*)(in + (size_t)row * NDIM + kc * 8);
    const float4 a = p[0], b = p[1];
    union { short8 s; __hip_bfloat162 h[4]; } t;
    t.h[0] = __float22bfloat162_rn(float2{a.x * SQS, a.y * SQS});
    t.h[1] = __float22bfloat162_rn(float2{a.z * SQS, a.w * SQS});
    t.h[2] = __float22bfloat162_rn(float2{b.x * SQS, b.y * SQS});
    t.h[3] = __float22bfloat162_rn(float2{b.z * SQS, b.w * SQS});
    ((short8*)fbT)[(size_t)kc * NROWS + row] = t.s;

    if (blockIdx.x == 0) {
        __shared__ int lab[512];
        lab[tid] = labels[tid];
        lab[tid + 256] = labels[tid + 256];
        if (tid == 0) out[0] = 0.0f;
        if (tid < 64) rbcnt[tid] = 0;
        __syncthreads();
        #pragma unroll 2
        for (int bb = tid; bb < 512; bb += 256) {
            const int my = lab[bb];
            int cnt = 0;
            #pragma unroll 8
            for (int k = 0; k < 512; ++k) cnt += (lab[k] == my) ? 1 : 0;
            pcount[bb] = 16.0f * (float)(cnt - 1);
        }
    }
}

// grid 2048: rb = blockIdx&63 (128 rows), q = blockIdx>>6 (256-col chunk)
__global__ __launch_bounds__(256, 6) void supcon_main(
    const unsigned short* __restrict__ fbT,
    const int* __restrict__ labels,
    const float* __restrict__ pcount,
    float* __restrict__ sM, float* __restrict__ sS, float* __restrict__ sP,
    int* __restrict__ rbcnt,
    float* __restrict__ out)
{
    __shared__ __align__(16) short stage[2][16 * 32 * 8];   // [buf][kc][col] 16B units, 8KB each
    __shared__ int clab[16];
    __shared__ float nredW[4];
    __shared__ int lastFlag;

    const int rb = blockIdx.x & 63;
    const int q  = blockIdx.x >> 6;
    const int rowBase = rb << 7;
    const int colBase = q << 8;
    const int tid = threadIdx.x;
    const int w = tid >> 6;
    const int lane = tid & 63;
    const int l15 = lane & 15;
    const int l4  = lane >> 4;
    const int kc_hi = lane >> 5;
    const int col_l = lane & 31;

    const short8* fb8 = (const short8*)fbT;

#define ISSUE(IT, BUF)                                                                   \
    {                                                                                    \
        unsigned short* sbase = (unsigned short*)&stage[BUF][0];                         \
        _Pragma("unroll")                                                                \
        for (int j = 0; j < 2; ++j) {                                                    \
            const int kcb = (w << 2) + (j << 1);                                         \
            const unsigned short* src = fbT +                                            \
                ((size_t)(kcb + kc_hi) * NROWS + colBase + ((IT) << 5) + col_l) * 8;     \
            __builtin_amdgcn_global_load_lds(                                            \
                (const __attribute__((address_space(1))) unsigned int*)src,              \
                (__attribute__((address_space(3))) unsigned int*)(sbase + kcb * 256),    \
                16, 0, 0);                                                               \
        }                                                                                \
    }

    ISSUE(0, 0)

    if (tid < 16) clab[tid] = labels[(colBase >> 4) + tid];

    // A fragments: wave owns 32 rows = 2 rowsets of 16; K=128 register-resident
    short8 afrag[2][4];
    int rw[2], brow[2], lrow[2];
    #pragma unroll
    for (int s = 0; s < 2; ++s) {
        rw[s]   = rowBase + w * 32 + s * 16;
        brow[s] = rw[s] >> 4;
        lrow[s] = labels[brow[s]];
        #pragma unroll
        for (int t = 0; t < 4; ++t)
            afrag[s][t] = fb8[(size_t)(t * 4 + l4) * NROWS + rw[s] + l15];
    }

    float tm[2][4], su[2][4], ps[2][4];
    #pragma unroll
    for (int s = 0; s < 2; ++s)
        #pragma unroll
        for (int r = 0; r < 4; ++r) { tm[s][r] = -1e30f; su[s][r] = 0.0f; ps[s][r] = 0.0f; }
    float noise_acc = 0.0f;

    __syncthreads();

    for (int it = 0; it < NITS; ++it) {
        if (it + 1 < NITS) ISSUE(it + 1, (it + 1) & 1)

        const short8* stv = (const short8*)stage[it & 1];
        floatx4 vacc[2][2];
        #pragma unroll
        for (int c = 0; c < 2; ++c) {
            short8 bfrag[4];
            #pragma unroll
            for (int t = 0; t < 4; ++t)
                bfrag[t] = stv[(t * 4 + l4) * 32 + c * 16 + l15];
            #pragma unroll
            for (int s = 0; s < 2; ++s) {
                floatx4 acc = {0.0f, 0.0f, 0.0f, 0.0f};
                #pragma unroll
                for (int t = 0; t < 4; ++t)
                    acc = __builtin_amdgcn_mfma_f32_16x16x32_bf16(afrag[s][t], bfrag[t], acc, 0, 0, 0);
                vacc[s][c] = acc;
            }
        }

        const int base16 = (colBase >> 4) + (it << 1);
        const int cl0 = clab[(it << 1)], cl1 = clab[(it << 1) + 1];
        #pragma unroll
        for (int s = 0; s < 2; ++s) {
            const int nt = brow[s] - base16;       // same-batch tile index if in [0,2)
            const bool anyn = ((unsigned)nt) < 2u; // wave-uniform, rare
            int posm = 0;
            if (cl0 == lrow[s] && nt != 0) posm |= 1;
            if (cl1 == lrow[s] && nt != 1) posm |= 2;
            #pragma unroll
            for (int r = 0; r < 4; ++r) {
                const float v0 = vacc[s][0][r], v1 = vacc[s][1][r];
                if (!anyn) {
                    // branchless online softmax: alpha==1 when max unchanged
                    const float tmr = tm[s][r];
                    const float tnm = fmaxf(tmr, fmaxf(v0, v1));
                    su[s][r] = fmaf(su[s][r], fexp2(tmr - tnm),
                                    fexp2(v0 - tnm) + fexp2(v1 - tnm));
                    tm[s][r] = tnm;
                } else {
                    const float vv = nt ? v0 : v1;   // valid tile
                    const float vn = nt ? v1 : v0;   // same-batch tile
                    const float tmr = tm[s][r];
                    const float tnm = fmaxf(tmr, vv);
                    su[s][r] = fmaf(su[s][r], fexp2(tmr - tnm), fexp2(vv - tnm));
                    tm[s][r] = tnm;
                    const int rl = (l4 << 2) + r;
                    if ((rl >> 3) == (l15 >> 3) && rl != l15) noise_acc += vn;
                }
                if (posm & 1) ps[s][r] += v0;
                if (posm & 2) ps[s][r] += v1;
            }
        }
        __syncthreads();
    }
#undef ISSUE

    // combine the 16 lane-partials per row via shuffles (l15 groups hold one row)
    #pragma unroll
    for (int s = 0; s < 2; ++s)
        #pragma unroll
        for (int r = 0; r < 4; ++r) {
            float tmv = tm[s][r], suv = su[s][r], psv = ps[s][r];
            #pragma unroll
            for (int off = 1; off < 16; off <<= 1) {
                float om = __shfl_xor(tmv, off);
                float os = __shfl_xor(suv, off);
                float op = __shfl_xor(psv, off);
                float nm = fmaxf(tmv, om);
                suv = suv * fexp2(tmv - nm) + os * fexp2(om - nm);
                tmv = nm; psv += op;
            }
            if (l15 == 0) {
                int row = rw[s] + (l4 << 2) + r;
                sM[row * NCH + q] = tmv;
                sS[row * NCH + q] = suv;
                sP[row * NCH + q] = psv;
            }
        }

    float na = noise_acc;
    #pragma unroll
    for (int off = 32; off >= 1; off >>= 1) na += __shfl_xor(na, off);
    if (lane == 0) nredW[w] = na;

    // release stats, bump row-group counter; last of 32 chunk-blocks merges
    __threadfence();
    __syncthreads();
    if (tid == 0) {
        atomicAdd(out, (nredW[0] + nredW[1] + nredW[2] + nredW[3]) * NOISE_COEF);
        int old = __hip_atomic_fetch_add(&rbcnt[rb], 1, __ATOMIC_ACQ_REL,
                                         __HIP_MEMORY_SCOPE_AGENT);
        lastFlag = (old == 31);
    }
    __syncthreads();

    if (lastFlag) {
        __shared__ float red[128];
        if (tid < 128) {
            const int row = rowBase + tid;
            const size_t base = (size_t)row * NCH;
            float gm = -1e30f;
            for (int qq = 0; qq < NCH; ++qq) {
                float m = __hip_atomic_load(&sM[base + qq], __ATOMIC_RELAXED,
                                            __HIP_MEMORY_SCOPE_AGENT);
                gm = fmaxf(gm, m);
            }
            float gs = 0.0f, gp = 0.0f;
            for (int qq = 0; qq < NCH; ++qq) {
                float m = __hip_atomic_load(&sM[base + qq], __ATOMIC_RELAXED,
                                            __HIP_MEMORY_SCOPE_AGENT);
                float s = __hip_atomic_load(&sS[base + qq], __ATOMIC_RELAXED,
                                            __HIP_MEMORY_SCOPE_AGENT);
                float p = __hip_atomic_load(&sP[base + qq], __ATOMIC_RELAXED,
                                            __HIP_MEMORY_SCOPE_AGENT);
                gs += s * fexp2(m - gm);
                gp += p;
            }
            const float P = pcount[row >> 4];
            red[tid] = LN2 * (P * (gm + __log2f(gs)) - gp) / (P + 1e-8f);
        }
        __syncthreads();
        if (tid < 64) { red[tid] += red[tid + 64]; }
        __syncthreads();
        if (tid < 32) {
            float v = red[tid] + red[tid + 32];
            #pragma unroll
            for (int off = 16; off >= 1; off >>= 1) v += __shfl_xor(v, off, 32);
            if (tid == 0) atomicAdd(out, v * CLASS_COEF);
        }
    }
}

extern "C" void kernel_launch(void* const* d_in, const int* in_sizes, int n_in,
                              void* d_out, int out_size, void* d_ws, size_t ws_size,
                              hipStream_t stream) {
    const float* feat  = (const float*)d_in[0];
    const int* labels  = (const int*)d_in[1];
    float* out = (float*)d_out;

    unsigned short* fbT = (unsigned short*)d_ws;                   // 2 MB bf16 transposed
    float* wsf    = (float*)((char*)d_ws + (size_t)NROWS * NDIM * 2);
    float* sM     = wsf;                    // 8192*32
    float* sS     = wsf + 262144;
    float* sP     = wsf + 524288;
    float* pcount = wsf + 786432;           // 512
    int*   rbcnt  = (int*)(wsf + 786944);   // 64

    hipLaunchKernelGGL(prep_kernel, dim3(512), dim3(256), 0, stream,
                       feat, labels, fbT, pcount, rbcnt, out);
    hipLaunchKernelGGL(supcon_main, dim3(2048), dim3(256), 0, stream,
                       fbT, labels, pcount, sM, sS, sP, rbcnt, out);
}

// Round 7
// 544.168 us; speedup vs baseline: 1.4531x; 1.4531x over previous
//
#include <hip/hip_runtime.h>
#include <hip/hip_bf16.h>

typedef __attribute__((ext_vector_type(8))) short short8;
typedef __attribute__((ext_vector_type(4))) float floatx4;

#define TINV 14.2857142857142857f               // 1/0.07
#define TL2  20.60992915555662f                  // TINV * log2(e)
#define LN2  0.6931471805599453f
#define SQS  4.539816022451927f                  // sqrt(TL2): dot(fb,fb) = TL2*dot(f,f)
#define NROWS 8192
#define NDIM 128
#define NCH 32                                   // 32 chunks x 256 cols
#define NITS 8                                   // 8 x 32 cols per chunk
#define CLASS_COEF (1.0f / (8192.0f * 3.0f))
#define NOISE_COEF (-LN2 / (57344.0f * 0.07f * 3.0f))

__device__ __forceinline__ float fexp2(float x) {
#if __has_builtin(__builtin_amdgcn_exp2f)
    return __builtin_amdgcn_exp2f(x);
#else
    return __expf(x * LN2);
#endif
}

// fp32 -> bf16 (pre-scaled by sqrt(TL2)) transposed into fbT[(kc*8192+row)*8];
// block 0 additionally computes pcount[512] and zeroes out + rbcnt.
__global__ void prep_kernel(const float* __restrict__ in, const int* __restrict__ labels,
                            unsigned short* __restrict__ fbT, float* __restrict__ pcount,
                            int* __restrict__ rbcnt, float* __restrict__ out) {
    const int tid = threadIdx.x;
    const int i = blockIdx.x * 256 + tid;       // 512 blocks: 131072 = 16 kc x 8192 rows
    const int kc = i >> 13;
    const int row = i & 8191;
    const float4* p = (const float4*)(in + (size_t)row * NDIM + kc * 8);
    const float4 a = p[0], b = p[1];
    union { short8 s; __hip_bfloat162 h[4]; } t;
    t.h[0] = __float22bfloat162_rn(float2{a.x * SQS, a.y * SQS});
    t.h[1] = __float22bfloat162_rn(float2{a.z * SQS, a.w * SQS});
    t.h[2] = __float22bfloat162_rn(float2{b.x * SQS, b.y * SQS});
    t.h[3] = __float22bfloat162_rn(float2{b.z * SQS, b.w * SQS});
    ((short8*)fbT)[(size_t)kc * NROWS + row] = t.s;

    if (blockIdx.x == 0) {
        __shared__ int lab[512];
        lab[tid] = labels[tid];
        lab[tid + 256] = labels[tid + 256];
        if (tid == 0) out[0] = 0.0f;
        if (tid < 64) rbcnt[tid] = 0;
        __syncthreads();
        #pragma unroll 2
        for (int bb = tid; bb < 512; bb += 256) {
            const int my = lab[bb];
            int cnt = 0;
            #pragma unroll 8
            for (int k = 0; k < 512; ++k) cnt += (lab[k] == my) ? 1 : 0;
            pcount[bb] = 16.0f * (float)(cnt - 1);
        }
    }
}

// grid 2048: rb = blockIdx&63 (128 rows), q = blockIdx>>6 (256-col chunk)
// NOTE: do NOT bound below 4 waves/EU — this kernel needs ~64 VGPRs;
// (256,6) forced VGPR=40 and spilled ~1 GB to scratch (R6: 738 us).
__global__ __launch_bounds__(256, 4) void supcon_main(
    const unsigned short* __restrict__ fbT,
    const int* __restrict__ labels,
    const float* __restrict__ pcount,
    float* __restrict__ sM, float* __restrict__ sS, float* __restrict__ sP,
    int* __restrict__ rbcnt,
    float* __restrict__ out)
{
    __shared__ __align__(16) short stage[2][16 * 32 * 8];   // [buf][kc][col] 16B units, 8KB each
    __shared__ int clab[16];
    __shared__ float nredW[4];
    __shared__ int lastFlag;

    const int rb = blockIdx.x & 63;
    const int q  = blockIdx.x >> 6;
    const int rowBase = rb << 7;
    const int colBase = q << 8;
    const int tid = threadIdx.x;
    const int w = tid >> 6;
    const int lane = tid & 63;
    const int l15 = lane & 15;
    const int l4  = lane >> 4;
    const int kc_hi = lane >> 5;
    const int col_l = lane & 31;

    const short8* fb8 = (const short8*)fbT;

#define ISSUE(IT, BUF)                                                                   \
    {                                                                                    \
        unsigned short* sbase = (unsigned short*)&stage[BUF][0];                         \
        _Pragma("unroll")                                                                \
        for (int j = 0; j < 2; ++j) {                                                    \
            const int kcb = (w << 2) + (j << 1);                                         \
            const unsigned short* src = fbT +                                            \
                ((size_t)(kcb + kc_hi) * NROWS + colBase + ((IT) << 5) + col_l) * 8;     \
            __builtin_amdgcn_global_load_lds(                                            \
                (const __attribute__((address_space(1))) unsigned int*)src,              \
                (__attribute__((address_space(3))) unsigned int*)(sbase + kcb * 256),    \
                16, 0, 0);                                                               \
        }                                                                                \
    }

    ISSUE(0, 0)

    if (tid < 16) clab[tid] = labels[(colBase >> 4) + tid];

    // A fragments: wave owns 32 rows = 2 rowsets of 16; K=128 register-resident
    short8 afrag[2][4];
    int rw[2], brow[2], lrow[2];
    #pragma unroll
    for (int s = 0; s < 2; ++s) {
        rw[s]   = rowBase + w * 32 + s * 16;
        brow[s] = rw[s] >> 4;
        lrow[s] = labels[brow[s]];
        #pragma unroll
        for (int t = 0; t < 4; ++t)
            afrag[s][t] = fb8[(size_t)(t * 4 + l4) * NROWS + rw[s] + l15];
    }

    float tm[2][4], su[2][4], ps[2][4];
    #pragma unroll
    for (int s = 0; s < 2; ++s)
        #pragma unroll
        for (int r = 0; r < 4; ++r) { tm[s][r] = -1e30f; su[s][r] = 0.0f; ps[s][r] = 0.0f; }
    float noise_acc = 0.0f;

    __syncthreads();

    for (int it = 0; it < NITS; ++it) {
        if (it + 1 < NITS) ISSUE(it + 1, (it + 1) & 1)

        const short8* stv = (const short8*)stage[it & 1];
        floatx4 vacc[2][2];
        #pragma unroll
        for (int c = 0; c < 2; ++c) {
            short8 bfrag[4];
            #pragma unroll
            for (int t = 0; t < 4; ++t)
                bfrag[t] = stv[(t * 4 + l4) * 32 + c * 16 + l15];
            #pragma unroll
            for (int s = 0; s < 2; ++s) {
                floatx4 acc = {0.0f, 0.0f, 0.0f, 0.0f};
                #pragma unroll
                for (int t = 0; t < 4; ++t)
                    acc = __builtin_amdgcn_mfma_f32_16x16x32_bf16(afrag[s][t], bfrag[t], acc, 0, 0, 0);
                vacc[s][c] = acc;
            }
        }

        const int base16 = (colBase >> 4) + (it << 1);
        const int cl0 = clab[(it << 1)], cl1 = clab[(it << 1) + 1];
        #pragma unroll
        for (int s = 0; s < 2; ++s) {
            const int nt = brow[s] - base16;       // same-batch tile index if in [0,2)
            const bool anyn = ((unsigned)nt) < 2u; // wave-uniform, rare
            int posm = 0;
            if (cl0 == lrow[s] && nt != 0) posm |= 1;
            if (cl1 == lrow[s] && nt != 1) posm |= 2;
            #pragma unroll
            for (int r = 0; r < 4; ++r) {
                const float v0 = vacc[s][0][r], v1 = vacc[s][1][r];
                if (!anyn) {
                    // branchless online softmax: alpha==1 when max unchanged
                    const float tmr = tm[s][r];
                    const float tnm = fmaxf(tmr, fmaxf(v0, v1));
                    su[s][r] = fmaf(su[s][r], fexp2(tmr - tnm),
                                    fexp2(v0 - tnm) + fexp2(v1 - tnm));
                    tm[s][r] = tnm;
                } else {
                    const float vv = nt ? v0 : v1;   // valid tile
                    const float vn = nt ? v1 : v0;   // same-batch tile
                    const float tmr = tm[s][r];
                    const float tnm = fmaxf(tmr, vv);
                    su[s][r] = fmaf(su[s][r], fexp2(tmr - tnm), fexp2(vv - tnm));
                    tm[s][r] = tnm;
                    const int rl = (l4 << 2) + r;
                    if ((rl >> 3) == (l15 >> 3) && rl != l15) noise_acc += vn;
                }
                if (posm & 1) ps[s][r] += v0;
                if (posm & 2) ps[s][r] += v1;
            }
        }
        __syncthreads();
    }
#undef ISSUE

    // combine the 16 lane-partials per row via shuffles (l15 groups hold one row)
    #pragma unroll
    for (int s = 0; s < 2; ++s)
        #pragma unroll
        for (int r = 0; r < 4; ++r) {
            float tmv = tm[s][r], suv = su[s][r], psv = ps[s][r];
            #pragma unroll
            for (int off = 1; off < 16; off <<= 1) {
                float om = __shfl_xor(tmv, off);
                float os = __shfl_xor(suv, off);
                float op = __shfl_xor(psv, off);
                float nm = fmaxf(tmv, om);
                suv = suv * fexp2(tmv - nm) + os * fexp2(om - nm);
                tmv = nm; psv += op;
            }
            if (l15 == 0) {
                int row = rw[s] + (l4 << 2) + r;
                sM[row * NCH + q] = tmv;
                sS[row * NCH + q] = suv;
                sP[row * NCH + q] = psv;
            }
        }

    float na = noise_acc;
    #pragma unroll
    for (int off = 32; off >= 1; off >>= 1) na += __shfl_xor(na, off);
    if (lane == 0) nredW[w] = na;

    // release stats, bump row-group counter; last of 32 chunk-blocks merges
    __threadfence();
    __syncthreads();
    if (tid == 0) {
        atomicAdd(out, (nredW[0] + nredW[1] + nredW[2] + nredW[3]) * NOISE_COEF);
        int old = __hip_atomic_fetch_add(&rbcnt[rb], 1, __ATOMIC_ACQ_REL,
                                         __HIP_MEMORY_SCOPE_AGENT);
        lastFlag = (old == 31);
    }
    __syncthreads();

    if (lastFlag) {
        __shared__ float red[128];
        if (tid < 128) {
            const int row = rowBase + tid;
            const size_t base = (size_t)row * NCH;
            float gm = -1e30f;
            for (int qq = 0; qq < NCH; ++qq) {
                float m = __hip_atomic_load(&sM[base + qq], __ATOMIC_RELAXED,
                                            __HIP_MEMORY_SCOPE_AGENT);
                gm = fmaxf(gm, m);
            }
            float gs = 0.0f, gp = 0.0f;
            for (int qq = 0; qq < NCH; ++qq) {
                float m = __hip_atomic_load(&sM[base + qq], __ATOMIC_RELAXED,
                                            __HIP_MEMORY_SCOPE_AGENT);
                float s = __hip_atomic_load(&sS[base + qq], __ATOMIC_RELAXED,
                                            __HIP_MEMORY_SCOPE_AGENT);
                float p = __hip_atomic_load(&sP[base + qq], __ATOMIC_RELAXED,
                                            __HIP_MEMORY_SCOPE_AGENT);
                gs += s * fexp2(m - gm);
                gp += p;
            }
            const float P = pcount[row >> 4];
            red[tid] = LN2 * (P * (gm + __log2f(gs)) - gp) / (P + 1e-8f);
        }
        __syncthreads();
        if (tid < 64) { red[tid] += red[tid + 64]; }
        __syncthreads();
        if (tid < 32) {
            float v = red[tid] + red[tid + 32];
            #pragma unroll
            for (int off = 16; off >= 1; off >>= 1) v += __shfl_xor(v, off, 32);
            if (tid == 0) atomicAdd(out, v * CLASS_COEF);
        }
    }
}

extern "C" void kernel_launch(void* const* d_in, const int* in_sizes, int n_in,
                              void* d_out, int out_size, void* d_ws, size_t ws_size,
                              hipStream_t stream) {
    const float* feat  = (const float*)d_in[0];
    const int* labels  = (const int*)d_in[1];
    float* out = (float*)d_out;

    unsigned short* fbT = (unsigned short*)d_ws;                   // 2 MB bf16 transposed
    float* wsf    = (float*)((char*)d_ws + (size_t)NROWS * NDIM * 2);
    float* sM     = wsf;                    // 8192*32
    float* sS     = wsf + 262144;
    float* sP     = wsf + 524288;
    float* pcount = wsf + 786432;           // 512
    int*   rbcnt  = (int*)(wsf + 786944);   // 64

    hipLaunchKernelGGL(prep_kernel, dim3(512), dim3(256), 0, stream,
                       feat, labels, fbT, pcount, rbcnt, out);
    hipLaunchKernelGGL(supcon_main, dim3(2048), dim3(256), 0, stream,
                       fbT, labels, pcount, sM, sS, sP, rbcnt, out);
}

// Round 8
// 241.166 us; speedup vs baseline: 3.2789x; 2.2564x over previous
//
#include <hip/hip_runtime.h>
#include <hip/hip_bf16.h>

typedef __attribute__((ext_vector_type(8))) short short8;
typedef __attribute__((ext_vector_type(4))) float floatx4;

#define TINV 14.2857142857142857f               // 1/0.07
#define LN2  0.6931471805599453f
#define SQS  4.539816022451927f                  // sqrt(TINV*log2 e): dot in log2-softmax domain
#define NROWS 8192
#define NDIM 128
#define NCH 32                                   // 32 chunks x 256 cols
#define NITS 8                                   // 8 x 32 cols per chunk
#define CLASS_COEF (1.0f / (8192.0f * 3.0f))
#define NOISE_COEF (-LN2 / (57344.0f * 0.07f * 3.0f))

__device__ __forceinline__ float fexp2(float x) {
#if __has_builtin(__builtin_amdgcn_exp2f)
    return __builtin_amdgcn_exp2f(x);
#else
    return __expf(x * LN2);
#endif
}

// fp32 -> bf16 (pre-scaled) transposed into fbT[(kc*8192+row)], 16B chunks, kc=k/8.
// Coalesced: consecutive tid -> consecutive kc within a row (contiguous 512B reads).
// Block 0 also computes pcount[512] and zeroes out.
__global__ void prep_kernel(const float* __restrict__ in, const int* __restrict__ labels,
                            unsigned short* __restrict__ fbT, float* __restrict__ pcount,
                            float* __restrict__ out) {
    const int tid = threadIdx.x;
    const int i = blockIdx.x * 256 + tid;       // 512 blocks: 131072 = 8192 rows x 16 kc
    const int kc = i & 15;
    const int row = i >> 4;
    const float4* p = (const float4*)(in + (size_t)row * NDIM + kc * 8);
    const float4 a = p[0], b = p[1];
    union { short8 s; __hip_bfloat162 h[4]; } t;
    t.h[0] = __float22bfloat162_rn(float2{a.x * SQS, a.y * SQS});
    t.h[1] = __float22bfloat162_rn(float2{a.z * SQS, a.w * SQS});
    t.h[2] = __float22bfloat162_rn(float2{b.x * SQS, b.y * SQS});
    t.h[3] = __float22bfloat162_rn(float2{b.z * SQS, b.w * SQS});
    ((short8*)fbT)[(size_t)kc * NROWS + row] = t.s;

    if (blockIdx.x == 0) {
        __shared__ int lab[512];
        lab[tid] = labels[tid];
        lab[tid + 256] = labels[tid + 256];
        if (tid == 0) out[0] = 0.0f;
        __syncthreads();
        #pragma unroll 2
        for (int bb = tid; bb < 512; bb += 256) {
            const int my = lab[bb];
            int cnt = 0;
            #pragma unroll 8
            for (int k = 0; k < 512; ++k) cnt += (lab[k] == my) ? 1 : 0;
            pcount[bb] = 16.0f * (float)(cnt - 1);
        }
    }
}

// grid 2048: rb = blockIdx&63 (128 rows), q = blockIdx>>6 (256-col chunk)
// NOTE: (256,4) only — (256,6) forced VGPR=40 and spilled ~1GB (R6).
// NOTE: no __threadfence / device-scope atomics here — they invalidate the XCD L2
// and re-fetch fbT endlessly (R7: 438 MB HBM traffic, 10x slowdown).
__global__ __launch_bounds__(256, 4) void supcon_main(
    const unsigned short* __restrict__ fbT,
    const int* __restrict__ labels,
    float* __restrict__ sM, float* __restrict__ sS, float* __restrict__ sP,
    float* __restrict__ noisep)
{
    __shared__ __align__(16) short stage[2][16 * 32 * 8];   // [buf][kc][col] 16B units, 8KB each
    __shared__ int clab[16];
    __shared__ float nredW[4];

    const int rb = blockIdx.x & 63;
    const int q  = blockIdx.x >> 6;
    const int rowBase = rb << 7;
    const int colBase = q << 8;
    const int tid = threadIdx.x;
    const int w = tid >> 6;
    const int lane = tid & 63;
    const int l15 = lane & 15;
    const int l4  = lane >> 4;
    const int kc_hi = lane >> 5;
    const int col_l = lane & 31;

    const short8* fb8 = (const short8*)fbT;

#define ISSUE(IT, BUF)                                                                   \
    {                                                                                    \
        unsigned short* sbase = (unsigned short*)&stage[BUF][0];                         \
        _Pragma("unroll")                                                                \
        for (int j = 0; j < 2; ++j) {                                                    \
            const int kcb = (w << 2) + (j << 1);                                         \
            const unsigned short* src = fbT +                                            \
                ((size_t)(kcb + kc_hi) * NROWS + colBase + ((IT) << 5) + col_l) * 8;     \
            __builtin_amdgcn_global_load_lds(                                            \
                (const __attribute__((address_space(1))) unsigned int*)src,              \
                (__attribute__((address_space(3))) unsigned int*)(sbase + kcb * 256),    \
                16, 0, 0);                                                               \
        }                                                                                \
    }

    ISSUE(0, 0)

    if (tid < 16) clab[tid] = labels[(colBase >> 4) + tid];

    // A fragments: wave owns 32 rows = 2 rowsets of 16; K=128 register-resident
    short8 afrag[2][4];
    int rw[2], brow[2], lrow[2];
    #pragma unroll
    for (int s = 0; s < 2; ++s) {
        rw[s]   = rowBase + w * 32 + s * 16;
        brow[s] = rw[s] >> 4;
        lrow[s] = labels[brow[s]];
        #pragma unroll
        for (int t = 0; t < 4; ++t)
            afrag[s][t] = fb8[(size_t)(t * 4 + l4) * NROWS + rw[s] + l15];
    }

    float tm[2][4], su[2][4], ps[2][4];
    #pragma unroll
    for (int s = 0; s < 2; ++s)
        #pragma unroll
        for (int r = 0; r < 4; ++r) { tm[s][r] = -1e30f; su[s][r] = 0.0f; ps[s][r] = 0.0f; }
    float noise_acc = 0.0f;

    __syncthreads();

    for (int it = 0; it < NITS; ++it) {
        if (it + 1 < NITS) ISSUE(it + 1, (it + 1) & 1)

        const short8* stv = (const short8*)stage[it & 1];
        floatx4 vacc[2][2];
        #pragma unroll
        for (int c = 0; c < 2; ++c) {
            short8 bfrag[4];
            #pragma unroll
            for (int t = 0; t < 4; ++t)
                bfrag[t] = stv[(t * 4 + l4) * 32 + c * 16 + l15];
            #pragma unroll
            for (int s = 0; s < 2; ++s) {
                floatx4 acc = {0.0f, 0.0f, 0.0f, 0.0f};
                #pragma unroll
                for (int t = 0; t < 4; ++t)
                    acc = __builtin_amdgcn_mfma_f32_16x16x32_bf16(afrag[s][t], bfrag[t], acc, 0, 0, 0);
                vacc[s][c] = acc;
            }
        }

        const int base16 = (colBase >> 4) + (it << 1);
        const int cl0 = clab[(it << 1)], cl1 = clab[(it << 1) + 1];
        #pragma unroll
        for (int s = 0; s < 2; ++s) {
            const int nt = brow[s] - base16;       // same-batch tile index if in [0,2)
            const bool anyn = ((unsigned)nt) < 2u; // wave-uniform, rare
            int posm = 0;
            if (cl0 == lrow[s] && nt != 0) posm |= 1;
            if (cl1 == lrow[s] && nt != 1) posm |= 2;
            #pragma unroll
            for (int r = 0; r < 4; ++r) {
                const float v0 = vacc[s][0][r], v1 = vacc[s][1][r];
                if (!anyn) {
                    // branchless online softmax: alpha==1 when max unchanged
                    const float tmr = tm[s][r];
                    const float tnm = fmaxf(tmr, fmaxf(v0, v1));
                    su[s][r] = fmaf(su[s][r], fexp2(tmr - tnm),
                                    fexp2(v0 - tnm) + fexp2(v1 - tnm));
                    tm[s][r] = tnm;
                } else {
                    const float vv = nt ? v0 : v1;   // valid tile
                    const float vn = nt ? v1 : v0;   // same-batch tile
                    const float tmr = tm[s][r];
                    const float tnm = fmaxf(tmr, vv);
                    su[s][r] = fmaf(su[s][r], fexp2(tmr - tnm), fexp2(vv - tnm));
                    tm[s][r] = tnm;
                    const int rl = (l4 << 2) + r;
                    if ((rl >> 3) == (l15 >> 3) && rl != l15) noise_acc += vn;
                }
                if (posm & 1) ps[s][r] += v0;
                if (posm & 2) ps[s][r] += v1;
            }
        }
        __syncthreads();
    }
#undef ISSUE

    // combine the 16 lane-partials per row via shuffles (l15 groups hold one row)
    #pragma unroll
    for (int s = 0; s < 2; ++s)
        #pragma unroll
        for (int r = 0; r < 4; ++r) {
            float tmv = tm[s][r], suv = su[s][r], psv = ps[s][r];
            #pragma unroll
            for (int off = 1; off < 16; off <<= 1) {
                float om = __shfl_xor(tmv, off);
                float os = __shfl_xor(suv, off);
                float op = __shfl_xor(psv, off);
                float nm = fmaxf(tmv, om);
                suv = suv * fexp2(tmv - nm) + os * fexp2(om - nm);
                tmv = nm; psv += op;
            }
            if (l15 == 0) {
                int row = rw[s] + (l4 << 2) + r;
                sM[row * NCH + q] = tmv;
                sS[row * NCH + q] = suv;
                sP[row * NCH + q] = psv;
            }
        }

    float na = noise_acc;
    #pragma unroll
    for (int off = 32; off >= 1; off >>= 1) na += __shfl_xor(na, off);
    if (lane == 0) nredW[w] = na;
    __syncthreads();
    if (tid == 0) noisep[blockIdx.x] = nredW[0] + nredW[1] + nredW[2] + nredW[3];
}

// 32 blocks x 256 threads: per-row online merge over 32 chunks + noise; atomicAdd to out
__global__ __launch_bounds__(256) void final_k(
    const float* __restrict__ sM, const float* __restrict__ sS, const float* __restrict__ sP,
    const float* __restrict__ pcount, const float* __restrict__ noisep,
    float* __restrict__ out)
{
    __shared__ float red[256];
    const int tid = threadIdx.x;
    const int row = blockIdx.x * 256 + tid;

    const float4* M4 = (const float4*)(sM + (size_t)row * NCH);
    const float4* S4 = (const float4*)(sS + (size_t)row * NCH);
    const float4* P4 = (const float4*)(sP + (size_t)row * NCH);
    float gm = -1e30f, gs = 0.0f, gp = 0.0f;
    #pragma unroll
    for (int j = 0; j < 8; ++j) {
        const float4 m = M4[j], s = S4[j], p = P4[j];
        // online merge, 4 lanes at a time
        float nm = fmaxf(fmaxf(gm, m.x), fmaxf(fmaxf(m.y, m.z), m.w));
        gs = gs * fexp2(gm - nm)
           + s.x * fexp2(m.x - nm) + s.y * fexp2(m.y - nm)
           + s.z * fexp2(m.z - nm) + s.w * fexp2(m.w - nm);
        gm = nm;
        gp += (p.x + p.y) + (p.z + p.w);
    }
    const float P = pcount[row >> 4];
    // log2-domain (pre-scaled features): term = LN2*(P*(gm+log2 gs) - possum)/(P+eps)
    float contrib = LN2 * (P * (gm + __log2f(gs)) - gp) / (P + 1e-8f) * CLASS_COEF;
    // 2048 noise partials: 64 per block
    if (tid < 64) contrib += noisep[blockIdx.x * 64 + tid] * NOISE_COEF;
    red[tid] = contrib;
    __syncthreads();
    #pragma unroll
    for (int off = 128; off > 0; off >>= 1) {
        if (tid < off) red[tid] += red[tid + off];
        __syncthreads();
    }
    if (tid == 0) atomicAdd(out, red[0]);
}

extern "C" void kernel_launch(void* const* d_in, const int* in_sizes, int n_in,
                              void* d_out, int out_size, void* d_ws, size_t ws_size,
                              hipStream_t stream) {
    const float* feat  = (const float*)d_in[0];
    const int* labels  = (const int*)d_in[1];
    float* out = (float*)d_out;

    unsigned short* fbT = (unsigned short*)d_ws;                   // 2 MB bf16 transposed
    float* wsf    = (float*)((char*)d_ws + (size_t)NROWS * NDIM * 2);
    float* sM     = wsf;                    // 8192*32
    float* sS     = wsf + 262144;
    float* sP     = wsf + 524288;
    float* pcount = wsf + 786432;           // 512
    float* noisep = wsf + 786944;           // 2048

    hipLaunchKernelGGL(prep_kernel, dim3(512), dim3(256), 0, stream,
                       feat, labels, fbT, pcount, out);
    hipLaunchKernelGGL(supcon_main, dim3(2048), dim3(256), 0, stream,
                       fbT, labels, sM, sS, sP, noisep);
    hipLaunchKernelGGL(final_k, dim3(32), dim3(256), 0, stream,
                       sM, sS, sP, pcount, noisep, out);
}

// Round 9
// 105.577 us; speedup vs baseline: 7.4898x; 2.2843x over previous
//
#include <hip/hip_runtime.h>
#include <hip/hip_bf16.h>

typedef __attribute__((ext_vector_type(8))) short short8;
typedef __attribute__((ext_vector_type(4))) float floatx4;

#define TINV 14.2857142857142857f               // 1/0.07
#define LN2  0.6931471805599453f
#define SQS  4.539816022451927f                  // sqrt(TINV*log2 e): dots land in log2-softmax domain
#define NROWS 8192
#define NDIM 128
#define NCH 16                                   // 16 chunks x 512 cols
#define NITS 16                                  // 16 x 32 cols per chunk
#define CLASS_COEF (1.0f / (8192.0f * 3.0f))
#define NOISE_COEF (-LN2 / (57344.0f * 0.07f * 3.0f))

__device__ __forceinline__ float fexp2(float x) {
#if __has_builtin(__builtin_amdgcn_exp2f)
    return __builtin_amdgcn_exp2f(x);
#else
    return __expf(x * LN2);
#endif
}

// fp32 -> bf16 (pre-scaled) transposed into fbT[(kc*8192+row)], 16B chunks, kc=k/8.
// Coalesced: consecutive tid -> consecutive kc within a row (contiguous 512B reads).
// Block 0 also computes pcount[512] and zeroes out.
__global__ void prep_kernel(const float* __restrict__ in, const int* __restrict__ labels,
                            unsigned short* __restrict__ fbT, float* __restrict__ pcount,
                            float* __restrict__ out) {
    const int tid = threadIdx.x;
    const int i = blockIdx.x * 256 + tid;       // 512 blocks: 131072 = 8192 rows x 16 kc
    const int kc = i & 15;
    const int row = i >> 4;
    const float4* p = (const float4*)(in + (size_t)row * NDIM + kc * 8);
    const float4 a = p[0], b = p[1];
    union { short8 s; __hip_bfloat162 h[4]; } t;
    t.h[0] = __float22bfloat162_rn(float2{a.x * SQS, a.y * SQS});
    t.h[1] = __float22bfloat162_rn(float2{a.z * SQS, a.w * SQS});
    t.h[2] = __float22bfloat162_rn(float2{b.x * SQS, b.y * SQS});
    t.h[3] = __float22bfloat162_rn(float2{b.z * SQS, b.w * SQS});
    ((short8*)fbT)[(size_t)kc * NROWS + row] = t.s;

    if (blockIdx.x == 0) {
        __shared__ int lab[512];
        lab[tid] = labels[tid];
        lab[tid + 256] = labels[tid + 256];
        if (tid == 0) out[0] = 0.0f;
        __syncthreads();
        #pragma unroll 2
        for (int bb = tid; bb < 512; bb += 256) {
            const int my = lab[bb];
            int cnt = 0;
            #pragma unroll 8
            for (int k = 0; k < 512; ++k) cnt += (lab[k] == my) ? 1 : 0;
            pcount[bb] = 16.0f * (float)(cnt - 1);
        }
    }
}

// grid 2048: rb = blockIdx&127 (64 rows), q = blockIdx>>7 (512-col chunk).
// Each wave owns 16 rows (ONE rowset) -> afrag 16 VGPRs, low pressure.
// NOTE: register cliff — R6/R7/R8 variants with 32 rows/wave spilled to scratch
// (0.4-1.0 GB HBM traffic). Keep per-thread arrays minimal; (256,4) only.
// NOTE: no __threadfence / device-scope atomics in the hot loop.
__global__ __launch_bounds__(256, 4) void supcon_main(
    const unsigned short* __restrict__ fbT,
    const int* __restrict__ labels,
    float* __restrict__ sM, float* __restrict__ sS, float* __restrict__ sP,
    float* __restrict__ noisep)
{
    __shared__ __align__(16) short stage[2][16 * 32 * 8];   // [buf][kc][col] 16B units, 8KB each
    __shared__ int clab[32];
    __shared__ float nredW[4];

    const int rb = blockIdx.x & 127;
    const int q  = blockIdx.x >> 7;
    const int rowBase = rb << 6;       // 64 rows per block
    const int colBase = q << 9;        // 512 cols per chunk
    const int tid = threadIdx.x;
    const int w = tid >> 6;
    const int lane = tid & 63;
    const int l15 = lane & 15;
    const int l4  = lane >> 4;
    const int kc_hi = lane >> 5;
    const int col_l = lane & 31;

    const short8* fb8 = (const short8*)fbT;

#define ISSUE(IT, BUF)                                                                   \
    {                                                                                    \
        unsigned short* sbase = (unsigned short*)&stage[BUF][0];                         \
        _Pragma("unroll")                                                                \
        for (int j = 0; j < 2; ++j) {                                                    \
            const int kcb = (w << 2) + (j << 1);                                         \
            const unsigned short* src = fbT +                                            \
                ((size_t)(kcb + kc_hi) * NROWS + colBase + ((IT) << 5) + col_l) * 8;     \
            __builtin_amdgcn_global_load_lds(                                            \
                (const __attribute__((address_space(1))) unsigned int*)src,              \
                (__attribute__((address_space(3))) unsigned int*)(sbase + kcb * 256),    \
                16, 0, 0);                                                               \
        }                                                                                \
    }

    ISSUE(0, 0)

    if (tid < 32) clab[tid] = labels[(colBase >> 4) + tid];

    // A fragments: wave owns 16 rows; K=128 register-resident (16 VGPRs)
    const int rw = rowBase + w * 16;
    const int brow = rw >> 4;
    const int lrow = labels[brow];
    short8 afrag[4];
    #pragma unroll
    for (int t = 0; t < 4; ++t)
        afrag[t] = fb8[(size_t)(t * 4 + l4) * NROWS + rw + l15];

    float tm[4], su[4], ps[4];
    #pragma unroll
    for (int r = 0; r < 4; ++r) { tm[r] = -1e30f; su[r] = 0.0f; ps[r] = 0.0f; }
    float noise_acc = 0.0f;

    __syncthreads();

    for (int it = 0; it < NITS; ++it) {
        if (it + 1 < NITS) ISSUE(it + 1, (it + 1) & 1)

        const short8* stv = (const short8*)stage[it & 1];
        floatx4 vacc[2];
        #pragma unroll
        for (int c = 0; c < 2; ++c) {
            short8 bfrag[4];
            #pragma unroll
            for (int t = 0; t < 4; ++t)
                bfrag[t] = stv[(t * 4 + l4) * 32 + c * 16 + l15];
            floatx4 acc = {0.0f, 0.0f, 0.0f, 0.0f};
            #pragma unroll
            for (int t = 0; t < 4; ++t)
                acc = __builtin_amdgcn_mfma_f32_16x16x32_bf16(afrag[t], bfrag[t], acc, 0, 0, 0);
            vacc[c] = acc;
        }

        const int base16 = (colBase >> 4) + (it << 1);
        const int cl0 = clab[(it << 1)], cl1 = clab[(it << 1) + 1];
        const int nt = brow - base16;          // same-batch tile index if in [0,2)
        const bool anyn = ((unsigned)nt) < 2u; // wave-uniform, rare
        int posm = 0;
        if (cl0 == lrow && nt != 0) posm |= 1;
        if (cl1 == lrow && nt != 1) posm |= 2;
        #pragma unroll
        for (int r = 0; r < 4; ++r) {
            const float v0 = vacc[0][r], v1 = vacc[1][r];
            if (!anyn) {
                // branchless online softmax: alpha==1 when max unchanged
                const float tmr = tm[r];
                const float tnm = fmaxf(tmr, fmaxf(v0, v1));
                su[r] = fmaf(su[r], fexp2(tmr - tnm), fexp2(v0 - tnm) + fexp2(v1 - tnm));
                tm[r] = tnm;
            } else {
                const float vv = nt ? v0 : v1;   // valid tile
                const float vn = nt ? v1 : v0;   // same-batch tile
                const float tmr = tm[r];
                const float tnm = fmaxf(tmr, vv);
                su[r] = fmaf(su[r], fexp2(tmr - tnm), fexp2(vv - tnm));
                tm[r] = tnm;
                const int rl = (l4 << 2) + r;
                if ((rl >> 3) == (l15 >> 3) && rl != l15) noise_acc += vn;
            }
            if (posm & 1) ps[r] += v0;
            if (posm & 2) ps[r] += v1;
        }
        __syncthreads();
    }
#undef ISSUE

    // combine the 16 lane-partials per row via shuffles (l15 groups hold one row)
    #pragma unroll
    for (int r = 0; r < 4; ++r) {
        float tmv = tm[r], suv = su[r], psv = ps[r];
        #pragma unroll
        for (int off = 1; off < 16; off <<= 1) {
            float om = __shfl_xor(tmv, off);
            float os = __shfl_xor(suv, off);
            float op = __shfl_xor(psv, off);
            float nm = fmaxf(tmv, om);
            suv = suv * fexp2(tmv - nm) + os * fexp2(om - nm);
            tmv = nm; psv += op;
        }
        if (l15 == 0) {
            int row = rw + (l4 << 2) + r;
            sM[row * NCH + q] = tmv;
            sS[row * NCH + q] = suv;
            sP[row * NCH + q] = psv;
        }
    }

    float na = noise_acc;
    #pragma unroll
    for (int off = 32; off >= 1; off >>= 1) na += __shfl_xor(na, off);
    if (lane == 0) nredW[w] = na;
    __syncthreads();
    if (tid == 0) noisep[blockIdx.x] = nredW[0] + nredW[1] + nredW[2] + nredW[3];
}

// 32 blocks x 256 threads: per-row online merge over 16 chunks + noise; atomicAdd to out
__global__ __launch_bounds__(256) void final_k(
    const float* __restrict__ sM, const float* __restrict__ sS, const float* __restrict__ sP,
    const float* __restrict__ pcount, const float* __restrict__ noisep,
    float* __restrict__ out)
{
    __shared__ float red[256];
    const int tid = threadIdx.x;
    const int row = blockIdx.x * 256 + tid;

    const float4* M4 = (const float4*)(sM + (size_t)row * NCH);
    const float4* S4 = (const float4*)(sS + (size_t)row * NCH);
    const float4* P4 = (const float4*)(sP + (size_t)row * NCH);
    float gm = -1e30f, gs = 0.0f, gp = 0.0f;
    #pragma unroll
    for (int j = 0; j < 4; ++j) {
        const float4 m = M4[j], s = S4[j], p = P4[j];
        float nm = fmaxf(fmaxf(gm, m.x), fmaxf(fmaxf(m.y, m.z), m.w));
        gs = gs * fexp2(gm - nm)
           + s.x * fexp2(m.x - nm) + s.y * fexp2(m.y - nm)
           + s.z * fexp2(m.z - nm) + s.w * fexp2(m.w - nm);
        gm = nm;
        gp += (p.x + p.y) + (p.z + p.w);
    }
    const float P = pcount[row >> 4];
    // log2-domain (pre-scaled features): term = LN2*(P*(gm+log2 gs) - possum)/(P+eps)
    float contrib = LN2 * (P * (gm + __log2f(gs)) - gp) / (P + 1e-8f) * CLASS_COEF;
    // 2048 noise partials: 64 per block
    if (tid < 64) contrib += noisep[blockIdx.x * 64 + tid] * NOISE_COEF;
    red[tid] = contrib;
    __syncthreads();
    #pragma unroll
    for (int off = 128; off > 0; off >>= 1) {
        if (tid < off) red[tid] += red[tid + off];
        __syncthreads();
    }
    if (tid == 0) atomicAdd(out, red[0]);
}

extern "C" void kernel_launch(void* const* d_in, const int* in_sizes, int n_in,
                              void* d_out, int out_size, void* d_ws, size_t ws_size,
                              hipStream_t stream) {
    const float* feat  = (const float*)d_in[0];
    const int* labels  = (const int*)d_in[1];
    float* out = (float*)d_out;

    unsigned short* fbT = (unsigned short*)d_ws;                   // 2 MB bf16 transposed
    float* wsf    = (float*)((char*)d_ws + (size_t)NROWS * NDIM * 2);
    float* sM     = wsf;                    // 8192*16
    float* sS     = wsf + 131072;
    float* sP     = wsf + 262144;
    float* pcount = wsf + 393216;           // 512
    float* noisep = wsf + 393728;           // 2048

    hipLaunchKernelGGL(prep_kernel, dim3(512), dim3(256), 0, stream,
                       feat, labels, fbT, pcount, out);
    hipLaunchKernelGGL(supcon_main, dim3(2048), dim3(256), 0, stream,
                       fbT, labels, sM, sS, sP, noisep);
    hipLaunchKernelGGL(final_k, dim3(32), dim3(256), 0, stream,
                       sM, sS, sP, pcount, noisep, out);
}